// Round 2
// baseline (254.275 us; speedup 1.0000x reference)
//
#include <hip/hip_runtime.h>
#include <hip/hip_bf16.h>

#define NTOK 1024     // tokens
#define TKN  2048     // expanded tokens (NTOK * topk)
#define NE   8        // experts
#define NRANK 4
#define IPR  1024     // intermediate per rank
#define HD   2048     // hidden
#define KD   4096     // NRANK * IPR
#define BM   64
#define BN   64
#define BK   64
#define XS   72       // LDS row stride (BK + 8 pad), 144 B rows -> 16B aligned
#define MAXTILES 40   // worst case sum ceil(c_e/64) = 39

typedef __bf16 bf16x8 __attribute__((ext_vector_type(8)));
typedef float f32x4 __attribute__((ext_vector_type(4)));
typedef unsigned short u16x8 __attribute__((ext_vector_type(8)));

static __device__ inline unsigned short f2b(float f) {
  return __builtin_bit_cast(unsigned short, __float2bfloat16(f));
}

// ---------------- zero d_out (harness doesn't re-zero between replays) ----------------
__global__ __launch_bounds__(256) void zero_kernel(float* __restrict__ p) {
  size_t i = ((size_t)blockIdx.x * 256 + threadIdx.x) * 4;
  *reinterpret_cast<float4*>(p + i) = float4{0.f, 0.f, 0.f, 0.f};
}

// ---------------- routing: top-2 + softmax gates + expert grouping ----------------
__global__ void routing_kernel(const float* __restrict__ logits,
                               float* __restrict__ gate,
                               int* __restrict__ perm,
                               int* __restrict__ tile_e,
                               int* __restrict__ tile_r0,
                               int* __restrict__ tile_nr) {
  __shared__ int cnt[NE];
  __shared__ int cur[NE];
  const int tid = threadIdx.x;   // one thread per token, 1024 threads
  if (tid < NE) cnt[tid] = 0;
  __syncthreads();

  float l[NE];
#pragma unroll
  for (int e = 0; e < NE; ++e) l[e] = logits[tid * NE + e];

  float v0 = l[0]; int i0 = 0;
  float v1 = -3.4e38f; int i1 = 0;
#pragma unroll
  for (int e = 1; e < NE; ++e) {
    if (l[e] > v0) { v1 = v0; i1 = i0; v0 = l[e]; i0 = e; }
    else if (l[e] > v1) { v1 = l[e]; i1 = e; }
  }
  float e1  = expf(v1 - v0);      // v1 <= v0
  float inv = 1.0f / (1.0f + e1);
  gate[2 * tid]     = inv;        // slot 0 = argmax
  gate[2 * tid + 1] = e1 * inv;   // slot 1

  atomicAdd(&cnt[i0], 1);
  atomicAdd(&cnt[i1], 1);
  __syncthreads();

  if (tid == 0) {
    int run = 0, nt = 0;
    for (int e = 0; e < NE; ++e) {
      cur[e] = run;
      int c = cnt[e];
      for (int r0 = 0; r0 < c; r0 += BM) {
        tile_e[nt]  = e;
        tile_r0[nt] = run + r0;
        tile_nr[nt] = (c - r0 < BM) ? (c - r0) : BM;
        ++nt;
      }
      run += c;
    }
    for (; nt < MAXTILES; ++nt) tile_e[nt] = -1;
  }
  __syncthreads();

  int p0 = atomicAdd(&cur[i0], 1); perm[p0] = 2 * tid;
  int p1 = atomicAdd(&cur[i1], 1); perm[p1] = 2 * tid + 1;
}

// ---------------- grouped GEMM: out[tk>>1][h] += gate[tk] * (x[tk] . W_e)[h] ----------------
__global__ __launch_bounds__(256) void gemm_kernel(
    const float* __restrict__ x,   // f32 [NRANK][TKN][IPR]
    const float* __restrict__ w,   // f32 [NRANK][NE][IPR][HD]
    const int* __restrict__ perm,
    const int* __restrict__ tile_e,
    const int* __restrict__ tile_r0,
    const int* __restrict__ tile_nr,
    const float* __restrict__ gate,
    float* __restrict__ out) {
  const int tile = blockIdx.x;
  const int e = tile_e[tile];
  if (e < 0) return;
  const int row0 = tile_r0[tile];
  const int nr   = tile_nr[tile];
  const int n0   = blockIdx.y * BN;

  __shared__ unsigned short Xs[BM][XS];   // bf16 bits, [m][k]
  __shared__ unsigned short Ws[BN][XS];   // bf16 bits, transposed: [n][k]

  const int tid  = threadIdx.x;
  const int lane = tid & 63;
  const int wid  = tid >> 6;
  const int wr   = wid >> 1;   // 0..1 : 32-row stripe
  const int wc   = wid & 1;    // 0..1 : 32-col stripe

  const int srow = tid >> 3;           // 0..31
  const int sc8  = (tid & 7) << 3;     // 0,8,...,56
  const int tka = (srow < nr)      ? perm[row0 + srow]      : -1;
  const int tkb = (srow + 32 < nr) ? perm[row0 + srow + 32] : -1;

  f32x4 acc[2][2];
#pragma unroll
  for (int a = 0; a < 2; ++a)
#pragma unroll
    for (int b = 0; b < 2; ++b) acc[a][b] = f32x4{0.f, 0.f, 0.f, 0.f};

  const int lrow = lane & 15;
  const int lk   = (lane >> 4) << 3;   // 0,8,16,24

  for (int kt = 0; kt < KD; kt += BK) {
    const int r  = kt >> 10;    // rank (BK=64 never straddles ranks)
    const int i0 = kt & 1023;

    // ---- stage X rows: f32 -> bf16 (zero-pad invalid rows) ----
    u16x8 xv0 = {0,0,0,0,0,0,0,0}, xv1 = {0,0,0,0,0,0,0,0};
    if (tka >= 0) {
      const float* p = x + ((size_t)r * TKN + tka) * IPR + i0 + sc8;
      float4 f0 = *reinterpret_cast<const float4*>(p);
      float4 f1 = *reinterpret_cast<const float4*>(p + 4);
      xv0[0]=f2b(f0.x); xv0[1]=f2b(f0.y); xv0[2]=f2b(f0.z); xv0[3]=f2b(f0.w);
      xv0[4]=f2b(f1.x); xv0[5]=f2b(f1.y); xv0[6]=f2b(f1.z); xv0[7]=f2b(f1.w);
    }
    if (tkb >= 0) {
      const float* p = x + ((size_t)r * TKN + tkb) * IPR + i0 + sc8;
      float4 f0 = *reinterpret_cast<const float4*>(p);
      float4 f1 = *reinterpret_cast<const float4*>(p + 4);
      xv1[0]=f2b(f0.x); xv1[1]=f2b(f0.y); xv1[2]=f2b(f0.z); xv1[3]=f2b(f0.w);
      xv1[4]=f2b(f1.x); xv1[5]=f2b(f1.y); xv1[6]=f2b(f1.z); xv1[7]=f2b(f1.w);
    }
    *reinterpret_cast<u16x8*>(&Xs[srow][sc8])      = xv0;
    *reinterpret_cast<u16x8*>(&Xs[srow + 32][sc8]) = xv1;

    // ---- stage W transposed: Ws[n][k] = bf16(W[k][n]) ----
    const size_t wbase = (((size_t)r * NE + e) * IPR + i0) * HD + (size_t)n0;
    {
      const float* p0 = w + wbase + (size_t)srow * HD + sc8;
      const float* p1 = w + wbase + (size_t)(srow + 32) * HD + sc8;
      float4 a0 = *reinterpret_cast<const float4*>(p0);
      float4 a1 = *reinterpret_cast<const float4*>(p0 + 4);
      float4 b0 = *reinterpret_cast<const float4*>(p1);
      float4 b1 = *reinterpret_cast<const float4*>(p1 + 4);
      Ws[sc8 + 0][srow] = f2b(a0.x); Ws[sc8 + 1][srow] = f2b(a0.y);
      Ws[sc8 + 2][srow] = f2b(a0.z); Ws[sc8 + 3][srow] = f2b(a0.w);
      Ws[sc8 + 4][srow] = f2b(a1.x); Ws[sc8 + 5][srow] = f2b(a1.y);
      Ws[sc8 + 6][srow] = f2b(a1.z); Ws[sc8 + 7][srow] = f2b(a1.w);
      Ws[sc8 + 0][srow + 32] = f2b(b0.x); Ws[sc8 + 1][srow + 32] = f2b(b0.y);
      Ws[sc8 + 2][srow + 32] = f2b(b0.z); Ws[sc8 + 3][srow + 32] = f2b(b0.w);
      Ws[sc8 + 4][srow + 32] = f2b(b1.x); Ws[sc8 + 5][srow + 32] = f2b(b1.y);
      Ws[sc8 + 6][srow + 32] = f2b(b1.z); Ws[sc8 + 7][srow + 32] = f2b(b1.w);
    }
    __syncthreads();

    // ---- compute: 2 k-steps of 32, 2x2 fragments per wave ----
#pragma unroll
    for (int ks = 0; ks < 2; ++ks) {
      bf16x8 af[2], bfr[2];
#pragma unroll
      for (int mi = 0; mi < 2; ++mi)
        af[mi] = __builtin_bit_cast(bf16x8,
            *reinterpret_cast<const u16x8*>(&Xs[wr * 32 + mi * 16 + lrow][ks * 32 + lk]));
#pragma unroll
      for (int ni = 0; ni < 2; ++ni)
        bfr[ni] = __builtin_bit_cast(bf16x8,
            *reinterpret_cast<const u16x8*>(&Ws[wc * 32 + ni * 16 + lrow][ks * 32 + lk]));
#pragma unroll
      for (int mi = 0; mi < 2; ++mi)
#pragma unroll
        for (int ni = 0; ni < 2; ++ni)
          acc[mi][ni] = __builtin_amdgcn_mfma_f32_16x16x32_bf16(af[mi], bfr[ni], acc[mi][ni], 0, 0, 0);
    }
    __syncthreads();
  }

  // ---- epilogue: gate * acc, atomicAdd into f32 out (exactly 2 adds/element -> deterministic) ----
  const int mbase = (lane >> 4) << 2;
#pragma unroll
  for (int mi = 0; mi < 2; ++mi) {
#pragma unroll
    for (int q = 0; q < 4; ++q) {
      const int m = wr * 32 + mi * 16 + mbase + q;
      if (m < nr) {
        const int tk = perm[row0 + m];
        const float g = gate[tk];
        float* dst = out + (size_t)(tk >> 1) * HD + n0 + wc * 32 + lrow;
#pragma unroll
        for (int ni = 0; ni < 2; ++ni)
          atomicAdd(&dst[ni * 16], g * acc[mi][ni][q]);
      }
    }
  }
}

extern "C" void kernel_launch(void* const* d_in, const int* in_sizes, int n_in,
                              void* d_out, int out_size, void* d_ws, size_t ws_size,
                              hipStream_t stream) {
  const float* x      = (const float*)d_in[0];  // f32 (upcast from fp16)
  const float* w      = (const float*)d_in[1];  // f32 (upcast from fp16)
  const float* logits = (const float*)d_in[2];
  // d_in[3] = topk (constant 2), unused

  char* ws = (char*)d_ws;
  float* gate    = (float*)(ws + 0);          // TKN floats   (8 KB)
  int*   perm    = (int*)(ws + 8192);         // TKN ints     (8 KB)
  int*   tile_e  = (int*)(ws + 16384);        // 40 ints
  int*   tile_r0 = (int*)(ws + 16384 + 256);
  int*   tile_nr = (int*)(ws + 16384 + 512);

  float* outf = (float*)d_out;                // f32 output [NTOK][HD]

  zero_kernel<<<(NTOK * HD / 4) / 256, 256, 0, stream>>>(outf);
  routing_kernel<<<1, 1024, 0, stream>>>(logits, gate, perm, tile_e, tile_r0, tile_nr);
  dim3 grid(MAXTILES, HD / BN);
  gemm_kernel<<<grid, 256, 0, stream>>>(x, w, perm, tile_e, tile_r0, tile_nr, gate, outf);
}

// Round 3
// 254.245 us; speedup vs baseline: 1.0001x; 1.0001x over previous
//
#include <hip/hip_runtime.h>
#include <hip/hip_bf16.h>

#define NTOK 1024     // tokens
#define TKN  2048     // expanded tokens (NTOK * topk)
#define NE   8        // experts
#define NRANK 4
#define IPR  1024     // intermediate per rank
#define HD   2048     // hidden
#define KD   4096     // NRANK * IPR
#define BM   128
#define BN   128
#define BK   64
#define XS   72       // LDS row stride in elements (144 B rows: 16B-aligned, odd multiple of 16B)
#define MAXTILES 24   // worst case sum ceil(c_e/128) = 23

typedef __bf16 bf16x8 __attribute__((ext_vector_type(8)));
typedef float f32x4 __attribute__((ext_vector_type(4)));
typedef unsigned short u16x8 __attribute__((ext_vector_type(8)));

static __device__ inline unsigned short f2b(float f) {
  return __builtin_bit_cast(unsigned short, __float2bfloat16(f));
}

// ---------------- zero d_out (harness doesn't re-zero between replays) ----------------
__global__ __launch_bounds__(256) void zero_kernel(float* __restrict__ p) {
  size_t i = ((size_t)blockIdx.x * 256 + threadIdx.x) * 4;
  *reinterpret_cast<float4*>(p + i) = float4{0.f, 0.f, 0.f, 0.f};
}

// ---------------- routing: top-2 + softmax gates + expert grouping ----------------
__global__ void routing_kernel(const float* __restrict__ logits,
                               float* __restrict__ gate,
                               int* __restrict__ perm,
                               int* __restrict__ tile_e,
                               int* __restrict__ tile_r0,
                               int* __restrict__ tile_nr) {
  __shared__ int cnt[NE];
  __shared__ int cur[NE];
  const int tid = threadIdx.x;   // one thread per token, 1024 threads
  if (tid < NE) cnt[tid] = 0;
  __syncthreads();

  float l[NE];
#pragma unroll
  for (int e = 0; e < NE; ++e) l[e] = logits[tid * NE + e];

  float v0 = l[0]; int i0 = 0;
  float v1 = -3.4e38f; int i1 = 0;
#pragma unroll
  for (int e = 1; e < NE; ++e) {
    if (l[e] > v0) { v1 = v0; i1 = i0; v0 = l[e]; i0 = e; }
    else if (l[e] > v1) { v1 = l[e]; i1 = e; }
  }
  float e1  = expf(v1 - v0);      // v1 <= v0
  float inv = 1.0f / (1.0f + e1);
  gate[2 * tid]     = inv;        // slot 0 = argmax
  gate[2 * tid + 1] = e1 * inv;   // slot 1

  atomicAdd(&cnt[i0], 1);
  atomicAdd(&cnt[i1], 1);
  __syncthreads();

  if (tid == 0) {
    int run = 0, nt = 0;
    for (int e = 0; e < NE; ++e) {
      cur[e] = run;
      int c = cnt[e];
      for (int r0 = 0; r0 < c; r0 += BM) {
        tile_e[nt]  = e;
        tile_r0[nt] = run + r0;
        tile_nr[nt] = (c - r0 < BM) ? (c - r0) : BM;
        ++nt;
      }
      run += c;
    }
    for (; nt < MAXTILES; ++nt) tile_e[nt] = -1;
  }
  __syncthreads();

  int p0 = atomicAdd(&cur[i0], 1); perm[p0] = 2 * tid;
  int p1 = atomicAdd(&cur[i1], 1); perm[p1] = 2 * tid + 1;
}

// ---------------- grouped GEMM: out[tk>>1][h] += gate[tk] * (x[tk] . W_e)[h] ----------------
__global__ __launch_bounds__(256) void gemm_kernel(
    const float* __restrict__ x,   // f32 [NRANK][TKN][IPR]
    const float* __restrict__ w,   // f32 [NRANK][NE][IPR][HD]
    const int* __restrict__ perm,
    const int* __restrict__ tile_e,
    const int* __restrict__ tile_r0,
    const int* __restrict__ tile_nr,
    const float* __restrict__ gate,
    float* __restrict__ out) {
  const int tile = blockIdx.x;
  const int e = tile_e[tile];
  if (e < 0) return;
  const int row0 = tile_r0[tile];
  const int nr   = tile_nr[tile];
  const int n0   = blockIdx.y * BN;

  __shared__ unsigned short Xs[BM][XS];   // bf16 bits, [m][k]
  __shared__ unsigned short Ws[BN][XS];   // bf16 bits, transposed: [n][k]

  const int tid  = threadIdx.x;
  const int lane = tid & 63;
  const int wid  = tid >> 6;
  const int wr   = wid >> 1;   // 0..1 : 64-row stripe
  const int wc   = wid & 1;    // 0..1 : 64-col stripe

  // ---- X staging coords: 4 passes; 8 threads per row, 32 B (8 f32) each ----
  const int xr = tid >> 3;          // 0..31 (row within pass)
  const int xc = (tid & 7) << 3;    // 0,8,...,56 (k-offset)
  int xtk[4];
#pragma unroll
  for (int p = 0; p < 4; ++p) {
    const int row = p * 32 + xr;
    xtk[p] = (row < nr) ? perm[row0 + row] : -1;
  }

  // ---- W staging coords: one n-column per thread-half, 32 k-values each ----
  const int wn = tid & 127;         // n within tile
  const int wk = (tid >> 7) << 5;   // 0 or 32 (k-half)

  f32x4 acc[4][4];
#pragma unroll
  for (int a = 0; a < 4; ++a)
#pragma unroll
    for (int b = 0; b < 4; ++b) acc[a][b] = f32x4{0.f, 0.f, 0.f, 0.f};

  const int lrow = lane & 15;
  const int lk   = (lane >> 4) << 3;   // 0,8,16,24

  for (int kt = 0; kt < KD; kt += BK) {
    const int r  = kt >> 10;    // rank (BK=64 never straddles ranks)
    const int i0 = kt & 1023;

    // ---- stage X: f32 -> bf16, row-major (zero-pad invalid rows) ----
#pragma unroll
    for (int p = 0; p < 4; ++p) {
      u16x8 v = {0,0,0,0,0,0,0,0};
      if (xtk[p] >= 0) {
        const float* src = x + ((size_t)r * TKN + xtk[p]) * IPR + i0 + xc;
        float4 f0 = *reinterpret_cast<const float4*>(src);
        float4 f1 = *reinterpret_cast<const float4*>(src + 4);
        v[0]=f2b(f0.x); v[1]=f2b(f0.y); v[2]=f2b(f0.z); v[3]=f2b(f0.w);
        v[4]=f2b(f1.x); v[5]=f2b(f1.y); v[6]=f2b(f1.z); v[7]=f2b(f1.w);
      }
      *reinterpret_cast<u16x8*>(&Xs[p * 32 + xr][xc]) = v;
    }

    // ---- stage W transposed via column loads: Ws[n][k] = bf16(W[k][n]) ----
    // Each dword load is coalesced across lanes (consecutive n, same k).
    {
      const float* wsrc = w + (((size_t)r * NE + e) * IPR + i0 + wk) * HD + n0 + wn;
#pragma unroll
      for (int g = 0; g < 4; ++g) {
        float v0 = wsrc[(size_t)(g * 8 + 0) * HD];
        float v1 = wsrc[(size_t)(g * 8 + 1) * HD];
        float v2 = wsrc[(size_t)(g * 8 + 2) * HD];
        float v3 = wsrc[(size_t)(g * 8 + 3) * HD];
        float v4 = wsrc[(size_t)(g * 8 + 4) * HD];
        float v5 = wsrc[(size_t)(g * 8 + 5) * HD];
        float v6 = wsrc[(size_t)(g * 8 + 6) * HD];
        float v7 = wsrc[(size_t)(g * 8 + 7) * HD];
        u16x8 pk;
        pk[0]=f2b(v0); pk[1]=f2b(v1); pk[2]=f2b(v2); pk[3]=f2b(v3);
        pk[4]=f2b(v4); pk[5]=f2b(v5); pk[6]=f2b(v6); pk[7]=f2b(v7);
        *reinterpret_cast<u16x8*>(&Ws[wn][wk + g * 8]) = pk;
      }
    }
    __syncthreads();

    // ---- compute: 2 k-steps of 32, 4x4 fragments per wave ----
#pragma unroll
    for (int ks = 0; ks < 2; ++ks) {
      bf16x8 af[4], bfr[4];
#pragma unroll
      for (int mi = 0; mi < 4; ++mi)
        af[mi] = __builtin_bit_cast(bf16x8,
            *reinterpret_cast<const u16x8*>(&Xs[wr * 64 + mi * 16 + lrow][ks * 32 + lk]));
#pragma unroll
      for (int ni = 0; ni < 4; ++ni)
        bfr[ni] = __builtin_bit_cast(bf16x8,
            *reinterpret_cast<const u16x8*>(&Ws[wc * 64 + ni * 16 + lrow][ks * 32 + lk]));
#pragma unroll
      for (int mi = 0; mi < 4; ++mi)
#pragma unroll
        for (int ni = 0; ni < 4; ++ni)
          acc[mi][ni] = __builtin_amdgcn_mfma_f32_16x16x32_bf16(af[mi], bfr[ni], acc[mi][ni], 0, 0, 0);
    }
    __syncthreads();
  }

  // ---- epilogue: gate * acc, atomicAdd into f32 out (exactly 2 adds/element) ----
  const int mb = (lane >> 4) << 2;
#pragma unroll
  for (int mi = 0; mi < 4; ++mi) {
#pragma unroll
    for (int q = 0; q < 4; ++q) {
      const int m = wr * 64 + mi * 16 + mb + q;
      if (m < nr) {
        const int tk = perm[row0 + m];
        const float g = gate[tk];
        float* dst = out + (size_t)(tk >> 1) * HD + n0 + wc * 64 + (lane & 15);
#pragma unroll
        for (int ni = 0; ni < 4; ++ni)
          atomicAdd(&dst[ni * 16], g * acc[mi][ni][q]);
      }
    }
  }
}

extern "C" void kernel_launch(void* const* d_in, const int* in_sizes, int n_in,
                              void* d_out, int out_size, void* d_ws, size_t ws_size,
                              hipStream_t stream) {
  const float* x      = (const float*)d_in[0];  // f32 (upcast from fp16)
  const float* w      = (const float*)d_in[1];  // f32 (upcast from fp16)
  const float* logits = (const float*)d_in[2];
  // d_in[3] = topk (constant 2), unused

  char* ws = (char*)d_ws;
  float* gate    = (float*)(ws + 0);          // TKN floats   (8 KB)
  int*   perm    = (int*)(ws + 8192);         // TKN ints     (8 KB)
  int*   tile_e  = (int*)(ws + 16384);        // MAXTILES ints
  int*   tile_r0 = (int*)(ws + 16384 + 256);
  int*   tile_nr = (int*)(ws + 16384 + 512);

  float* outf = (float*)d_out;                // f32 output [NTOK][HD]

  zero_kernel<<<(NTOK * HD / 4) / 256, 256, 0, stream>>>(outf);
  routing_kernel<<<1, 1024, 0, stream>>>(logits, gate, perm, tile_e, tile_r0, tile_nr);
  dim3 grid(MAXTILES, HD / BN);
  gemm_kernel<<<grid, 256, 0, stream>>>(x, w, perm, tile_e, tile_r0, tile_nr, gate, outf);
}

// Round 4
// 172.680 us; speedup vs baseline: 1.4725x; 1.4723x over previous
//
#include <hip/hip_runtime.h>
#include <hip/hip_bf16.h>

#define NTOK 1024     // tokens
#define TKN  2048     // expanded tokens (NTOK * topk)
#define NE   8        // experts
#define NRANK 4
#define IPR  1024     // intermediate per rank
#define HD   2048     // hidden
#define KD   4096     // NRANK * IPR
#define BM   128
#define BN   64
#define BK   64
#define NIT  (KD / BK)   // 64 k-iterations
#define XS   72       // LDS row stride in elements (144 B rows)
#define MAXTILES 24   // worst case sum ceil(c_e/128) = 23

typedef __bf16 bf16x8 __attribute__((ext_vector_type(8)));
typedef float f32x4 __attribute__((ext_vector_type(4)));
typedef unsigned short u16x8 __attribute__((ext_vector_type(8)));

static __device__ inline unsigned short f2b(float f) {
  return __builtin_bit_cast(unsigned short, __float2bfloat16(f));
}

// ---------------- zero d_out (harness doesn't re-zero between replays) ----------------
__global__ __launch_bounds__(256) void zero_kernel(float* __restrict__ p) {
  size_t i = ((size_t)blockIdx.x * 256 + threadIdx.x) * 4;
  *reinterpret_cast<float4*>(p + i) = float4{0.f, 0.f, 0.f, 0.f};
}

// ---------------- routing: top-2 + softmax gates + expert grouping ----------------
__global__ void routing_kernel(const float* __restrict__ logits,
                               float* __restrict__ gate,
                               int* __restrict__ perm,
                               int* __restrict__ tile_e,
                               int* __restrict__ tile_r0,
                               int* __restrict__ tile_nr) {
  __shared__ int cnt[NE];
  __shared__ int cur[NE];
  const int tid = threadIdx.x;   // one thread per token, 1024 threads
  if (tid < NE) cnt[tid] = 0;
  __syncthreads();

  float l[NE];
#pragma unroll
  for (int e = 0; e < NE; ++e) l[e] = logits[tid * NE + e];

  float v0 = l[0]; int i0 = 0;
  float v1 = -3.4e38f; int i1 = 0;
#pragma unroll
  for (int e = 1; e < NE; ++e) {
    if (l[e] > v0) { v1 = v0; i1 = i0; v0 = l[e]; i0 = e; }
    else if (l[e] > v1) { v1 = l[e]; i1 = e; }
  }
  float e1  = expf(v1 - v0);      // v1 <= v0
  float inv = 1.0f / (1.0f + e1);
  gate[2 * tid]     = inv;        // slot 0 = argmax
  gate[2 * tid + 1] = e1 * inv;   // slot 1

  atomicAdd(&cnt[i0], 1);
  atomicAdd(&cnt[i1], 1);
  __syncthreads();

  if (tid == 0) {
    int run = 0, nt = 0;
    for (int e = 0; e < NE; ++e) {
      cur[e] = run;
      int c = cnt[e];
      for (int r0 = 0; r0 < c; r0 += BM) {
        tile_e[nt]  = e;
        tile_r0[nt] = run + r0;
        tile_nr[nt] = (c - r0 < BM) ? (c - r0) : BM;
        ++nt;
      }
      run += c;
    }
    for (; nt < MAXTILES; ++nt) tile_e[nt] = -1;
  }
  __syncthreads();

  int p0 = atomicAdd(&cur[i0], 1); perm[p0] = 2 * tid;
  int p1 = atomicAdd(&cur[i1], 1); perm[p1] = 2 * tid + 1;
}

// ---------------- grouped GEMM: out[tk>>1][h] += gate[tk] * (x[tk] . W_e)[h] ----------------
__global__ __launch_bounds__(256, 3) void gemm_kernel(
    const float* __restrict__ x,   // f32 [NRANK][TKN][IPR]
    const float* __restrict__ w,   // f32 [NRANK][NE][IPR][HD]
    const int* __restrict__ perm,
    const int* __restrict__ tile_e,
    const int* __restrict__ tile_r0,
    const int* __restrict__ tile_nr,
    const float* __restrict__ gate,
    float* __restrict__ out) {
  const int tile = blockIdx.x;
  const int e = tile_e[tile];
  if (e < 0) return;
  const int row0 = tile_r0[tile];
  const int nr   = tile_nr[tile];
  const int n0   = blockIdx.y * BN;

  __shared__ unsigned short Xs[BM][XS];   // bf16 bits, [m][k]
  __shared__ unsigned short Ws[BN][XS];   // bf16 bits, transposed: [n][k]

  const int tid  = threadIdx.x;
  const int lane = tid & 63;
  const int wid  = tid >> 6;
  const int wr   = wid >> 1;   // 0..1 : 64-row stripe
  const int wc   = wid & 1;    // 0..1 : 32-col stripe

  // ---- X staging coords: 4 passes; 8 threads per row, 32 B (8 f32) each ----
  const int xr = tid >> 3;          // 0..31 (row within pass)
  const int xc = (tid & 7) << 3;    // k-offset 0,8,...,56
  int xtk[4];
#pragma unroll
  for (int p = 0; p < 4; ++p) {
    const int row = p * 32 + xr;
    xtk[p] = (row < nr) ? perm[row0 + row] : -1;
  }

  // ---- W staging coords: one n-column per thread, 16 k-values ----
  const int wn  = tid & 63;          // n within tile (wave lanes -> consecutive n)
  const int wkq = (tid >> 6) << 4;   // 0,16,32,48 (k-quarter per wave)

  // prefetch registers
  float4 xf[4][2];
  float  wv[16];

#define LOADREGS(KT) do {                                                        \
    const int r_  = (KT) >> 10;                                                  \
    const int i0_ = (KT) & 1023;                                                 \
    _Pragma("unroll")                                                            \
    for (int p_ = 0; p_ < 4; ++p_) {                                             \
      if (xtk[p_] >= 0) {                                                        \
        const float* sp_ = x + ((size_t)r_ * TKN + xtk[p_]) * IPR + i0_ + xc;    \
        xf[p_][0] = *reinterpret_cast<const float4*>(sp_);                       \
        xf[p_][1] = *reinterpret_cast<const float4*>(sp_ + 4);                   \
      } else {                                                                   \
        xf[p_][0] = float4{0.f, 0.f, 0.f, 0.f};                                  \
        xf[p_][1] = float4{0.f, 0.f, 0.f, 0.f};                                  \
      }                                                                          \
    }                                                                            \
    const float* wp_ = w + (((size_t)r_ * NE + e) * IPR + i0_ + wkq) * HD + n0 + wn; \
    _Pragma("unroll")                                                            \
    for (int j_ = 0; j_ < 16; ++j_) wv[j_] = wp_[(size_t)j_ * HD];               \
  } while (0)

  f32x4 acc[4][2];
#pragma unroll
  for (int a = 0; a < 4; ++a)
#pragma unroll
    for (int b = 0; b < 2; ++b) acc[a][b] = f32x4{0.f, 0.f, 0.f, 0.f};

  const int lrow = lane & 15;
  const int lk   = (lane >> 4) << 3;   // 0,8,16,24

  LOADREGS(0);

  for (int t = 0; t < NIT; ++t) {
    __syncthreads();   // previous compute done; LDS free

    // ---- write prefetched regs -> LDS (f32 -> bf16) ----
#pragma unroll
    for (int p = 0; p < 4; ++p) {
      u16x8 v;
      v[0] = f2b(xf[p][0].x); v[1] = f2b(xf[p][0].y);
      v[2] = f2b(xf[p][0].z); v[3] = f2b(xf[p][0].w);
      v[4] = f2b(xf[p][1].x); v[5] = f2b(xf[p][1].y);
      v[6] = f2b(xf[p][1].z); v[7] = f2b(xf[p][1].w);
      *reinterpret_cast<u16x8*>(&Xs[p * 32 + xr][xc]) = v;
    }
    {
      u16x8 a, b;
      a[0] = f2b(wv[0]);  a[1] = f2b(wv[1]);  a[2] = f2b(wv[2]);  a[3] = f2b(wv[3]);
      a[4] = f2b(wv[4]);  a[5] = f2b(wv[5]);  a[6] = f2b(wv[6]);  a[7] = f2b(wv[7]);
      b[0] = f2b(wv[8]);  b[1] = f2b(wv[9]);  b[2] = f2b(wv[10]); b[3] = f2b(wv[11]);
      b[4] = f2b(wv[12]); b[5] = f2b(wv[13]); b[6] = f2b(wv[14]); b[7] = f2b(wv[15]);
      *reinterpret_cast<u16x8*>(&Ws[wn][wkq])     = a;
      *reinterpret_cast<u16x8*>(&Ws[wn][wkq + 8]) = b;
    }
    __syncthreads();   // LDS ready

    // ---- prefetch next iteration (overlaps compute below) ----
    if (t + 1 < NIT) LOADREGS((t + 1) * BK);

    // ---- compute: 2 k-steps of 32, 4x2 fragments per wave ----
#pragma unroll
    for (int ks = 0; ks < 2; ++ks) {
      bf16x8 af[4], bfr[2];
#pragma unroll
      for (int mi = 0; mi < 4; ++mi)
        af[mi] = __builtin_bit_cast(bf16x8,
            *reinterpret_cast<const u16x8*>(&Xs[wr * 64 + mi * 16 + lrow][ks * 32 + lk]));
#pragma unroll
      for (int ni = 0; ni < 2; ++ni)
        bfr[ni] = __builtin_bit_cast(bf16x8,
            *reinterpret_cast<const u16x8*>(&Ws[wc * 32 + ni * 16 + lrow][ks * 32 + lk]));
#pragma unroll
      for (int mi = 0; mi < 4; ++mi)
#pragma unroll
        for (int ni = 0; ni < 2; ++ni)
          acc[mi][ni] = __builtin_amdgcn_mfma_f32_16x16x32_bf16(af[mi], bfr[ni], acc[mi][ni], 0, 0, 0);
    }
  }

  // ---- epilogue: gate * acc, atomicAdd into f32 out (exactly 2 adds/element) ----
  const int mb = (lane >> 4) << 2;
#pragma unroll
  for (int mi = 0; mi < 4; ++mi) {
#pragma unroll
    for (int q = 0; q < 4; ++q) {
      const int m = wr * 64 + mi * 16 + mb + q;
      if (m < nr) {
        const int tk = perm[row0 + m];
        const float g = gate[tk];
        float* dst = out + (size_t)(tk >> 1) * HD + n0 + wc * 32 + (lane & 15);
#pragma unroll
        for (int ni = 0; ni < 2; ++ni)
          atomicAdd(&dst[ni * 16], g * acc[mi][ni][q]);
      }
    }
  }
#undef LOADREGS
}

extern "C" void kernel_launch(void* const* d_in, const int* in_sizes, int n_in,
                              void* d_out, int out_size, void* d_ws, size_t ws_size,
                              hipStream_t stream) {
  const float* x      = (const float*)d_in[0];  // f32 (upcast from fp16)
  const float* w      = (const float*)d_in[1];  // f32 (upcast from fp16)
  const float* logits = (const float*)d_in[2];
  // d_in[3] = topk (constant 2), unused

  char* ws = (char*)d_ws;
  float* gate    = (float*)(ws + 0);          // TKN floats   (8 KB)
  int*   perm    = (int*)(ws + 8192);         // TKN ints     (8 KB)
  int*   tile_e  = (int*)(ws + 16384);        // MAXTILES ints
  int*   tile_r0 = (int*)(ws + 16384 + 256);
  int*   tile_nr = (int*)(ws + 16384 + 512);

  float* outf = (float*)d_out;                // f32 output [NTOK][HD]

  zero_kernel<<<(NTOK * HD / 4) / 256, 256, 0, stream>>>(outf);
  routing_kernel<<<1, 1024, 0, stream>>>(logits, gate, perm, tile_e, tile_r0, tile_nr);
  dim3 grid(MAXTILES, HD / BN);
  gemm_kernel<<<grid, 256, 0, stream>>>(x, w, perm, tile_e, tile_r0, tile_nr, gate, outf);
}